// Round 3
// baseline (26.497 us; speedup 1.0000x reference)
//
#include <hip/hip_runtime.h>
#include <math.h>

#define M_CP   256
#define N_PTS  32768
#define BATCH  4

// Prep: build SoA tables in workspace.
// tabA[b*M+m] = (-2*cx, -2*cy, -2*cz, |c|^2)      (r^2 expansion coeffs)
// tabB[b*M+m] = (sx*k, sy*k, sz*k, 0)  k = ln2/2  (folded TPS constant)
__global__ __launch_bounds__(256) void rbf_prep(
    const float* __restrict__ sparse_disp,   // (B, M, 3)
    const float* __restrict__ original_cp,   // (B, M, 3)
    float4* __restrict__ tabA,
    float4* __restrict__ tabB)
{
    int i = blockIdx.x * 256 + threadIdx.x;
    if (i >= BATCH * M_CP) return;
    float cx = original_cp[i * 3 + 0];
    float cy = original_cp[i * 3 + 1];
    float cz = original_cp[i * 3 + 2];
    const float k = 0.34657359027997264f;    // 0.5 * ln(2)
    tabA[i] = make_float4(-2.f * cx, -2.f * cy, -2.f * cz,
                          fmaf(cx, cx, fmaf(cy, cy, cz * cz)));
    tabB[i] = make_float4(sparse_disp[i * 3 + 0] * k,
                          sparse_disp[i * 3 + 1] * k,
                          sparse_disp[i * 3 + 2] * k, 0.f);
}

// Main: one thread per dense point. Control-point table is wave-uniform ->
// compiler emits s_load into SGPRs; inner loop has ZERO LDS/VMEM per-lane ops.
// K_ref = r^2 * ln(r + 1e-6) ~= r^2 * (ln2/2) * log2(r^2), constant folded
// into tabB. r^2 = |p|^2 + (p . -2c + |c|^2) via the expanded form.
__global__ __launch_bounds__(256) void rbf_main(
    const float* __restrict__ original_dense, // (B, N, 3)
    const float4* __restrict__ tabA,
    const float4* __restrict__ tabB,
    float* __restrict__ out)                  // (B, N, 3)
{
    const int blocks_per_b = N_PTS / 256;     // 128
    const int b = blockIdx.x / blocks_per_b;
    const int n = (blockIdx.x % blocks_per_b) * 256 + threadIdx.x;

    const float* dp = original_dense + ((size_t)b * N_PTS + n) * 3;
    const float px = dp[0], py = dp[1], pz = dp[2];
    const float pp = fmaf(px, px, fmaf(py, py, pz * pz));

    const float4* __restrict__ A = tabA + b * M_CP;
    const float4* __restrict__ S = tabB + b * M_CP;

    float ax = 0.f, ay = 0.f, az = 0.f;

    #pragma unroll 8
    for (int m = 0; m < M_CP; ++m) {
        float4 a = A[m];                      // uniform -> s_load
        float4 s = S[m];                      // uniform -> s_load
        float r2 = fmaf(px, a.x, fmaf(py, a.y, fmaf(pz, a.z, a.w))) + pp;
        r2 = fmaxf(r2, 1e-12f);               // guard cancellation/underflow
        float K = r2 * __log2f(r2);
        ax = fmaf(K, s.x, ax);
        ay = fmaf(K, s.y, ay);
        az = fmaf(K, s.z, az);
    }

    float* op = out + ((size_t)b * N_PTS + n) * 3;
    op[0] = ax; op[1] = ay; op[2] = az;
}

extern "C" void kernel_launch(void* const* d_in, const int* in_sizes, int n_in,
                              void* d_out, int out_size, void* d_ws, size_t ws_size,
                              hipStream_t stream) {
    const float* sparse_disp    = (const float*)d_in[0];
    const float* original_cp    = (const float*)d_in[1];
    const float* original_dense = (const float*)d_in[2];
    float* out = (float*)d_out;

    float4* tabA = (float4*)d_ws;                       // 16 KB
    float4* tabB = (float4*)((char*)d_ws + 16384);      // 16 KB

    rbf_prep<<<dim3((BATCH * M_CP + 255) / 256), dim3(256), 0, stream>>>(
        sparse_disp, original_cp, tabA, tabB);
    rbf_main<<<dim3(BATCH * (N_PTS / 256)), dim3(256), 0, stream>>>(
        original_dense, tabA, tabB, out);
}

// Round 4
// 16.518 us; speedup vs baseline: 1.6041x; 1.6041x over previous
//
#include <hip/hip_runtime.h>
#include <math.h>

#define M_CP   256
#define N_PTS  32768
#define BATCH  4

// Block: 256 threads = 4 waves. Each block: 128 dense points, all 256 m.
// Wave w handles m in [w*64, w*64+64) for all 128 points (2 points/thread),
// partials reduced via LDS. 1024 blocks -> 4 blocks/CU -> 4 waves/SIMD.
__global__ __launch_bounds__(256, 4) void rbf_tps_kernel(
    const float* __restrict__ sparse_disp,   // (B, M, 3)
    const float* __restrict__ original_cp,   // (B, M, 3)
    const float* __restrict__ original_dense,// (B, N, 3)
    float* __restrict__ out)                 // (B, N, 3)
{
    __shared__ float ax[M_CP], ay[M_CP], az[M_CP], aw[M_CP];  // -2c, |c|^2
    __shared__ float sx[M_CP], sy[M_CP], sz[M_CP];            // disp * ln2/2
    __shared__ float red[4][64][6];                           // 6 KB partials

    const int t = threadIdx.x;
    const int blocks_per_b = 256;                 // 32768/128
    const int b     = blockIdx.x / blocks_per_b;
    const int nbase = (blockIdx.x % blocks_per_b) * 128;

    // Stage: thread t preps control point t.
    // K_ref = r^2*ln(r+1e-6) ~= r^2*(ln2/2)*log2(r^2); fold ln2/2 into s.
    // r^2 = |p|^2 + p.(-2c) + |c|^2  (expanded form: 4 FMA-class ops)
    {
        const float* cpb = original_cp + (size_t)b * M_CP * 3;
        const float* sdb = sparse_disp + (size_t)b * M_CP * 3;
        float cx = cpb[t * 3 + 0], cy = cpb[t * 3 + 1], cz = cpb[t * 3 + 2];
        ax[t] = -2.f * cx; ay[t] = -2.f * cy; az[t] = -2.f * cz;
        aw[t] = fmaf(cx, cx, fmaf(cy, cy, cz * cz));
        const float k = 0.34657359027997264f;     // 0.5*ln(2)
        sx[t] = sdb[t * 3 + 0] * k;
        sy[t] = sdb[t * 3 + 1] * k;
        sz[t] = sdb[t * 3 + 2] * k;
    }
    __syncthreads();

    const int wave = t >> 6;      // m-chunk id
    const int lane = t & 63;
    const int mlo  = wave * 64;

    const int n0 = nbase + lane;        // point 0
    const int n1 = nbase + 64 + lane;   // point 1

    const float* dp0 = original_dense + ((size_t)b * N_PTS + n0) * 3;
    const float* dp1 = original_dense + ((size_t)b * N_PTS + n1) * 3;
    const float px0 = dp0[0], py0 = dp0[1], pz0 = dp0[2];
    const float px1 = dp1[0], py1 = dp1[1], pz1 = dp1[2];
    const float pp0 = fmaf(px0, px0, fmaf(py0, py0, pz0 * pz0));
    const float pp1 = fmaf(px1, px1, fmaf(py1, py1, pz1 * pz1));

    float ax0 = 0.f, ay0 = 0.f, az0 = 0.f;
    float ax1 = 0.f, ay1 = 0.f, az1 = 0.f;

    #pragma unroll 2
    for (int mm = 0; mm < 64; mm += 4) {
        const int m = mlo + mm;
        float4 vax = *(const float4*)&ax[m];
        float4 vay = *(const float4*)&ay[m];
        float4 vaz = *(const float4*)&az[m];
        float4 vaw = *(const float4*)&aw[m];
        float4 vsx = *(const float4*)&sx[m];
        float4 vsy = *(const float4*)&sy[m];
        float4 vsz = *(const float4*)&sz[m];

        const float AX[4] = {vax.x, vax.y, vax.z, vax.w};
        const float AY[4] = {vay.x, vay.y, vay.z, vay.w};
        const float AZ[4] = {vaz.x, vaz.y, vaz.z, vaz.w};
        const float AW[4] = {vaw.x, vaw.y, vaw.z, vaw.w};
        const float SX[4] = {vsx.x, vsx.y, vsx.z, vsx.w};
        const float SY[4] = {vsy.x, vsy.y, vsy.z, vsy.w};
        const float SZ[4] = {vsz.x, vsz.y, vsz.z, vsz.w};

        #pragma unroll
        for (int k = 0; k < 4; ++k) {
            float r20 = fmaf(px0, AX[k], fmaf(py0, AY[k],
                        fmaf(pz0, AZ[k], AW[k] + pp0)));
            r20 = fmaxf(r20, 1e-12f);
            float K0 = r20 * __log2f(r20);
            ax0 = fmaf(K0, SX[k], ax0);
            ay0 = fmaf(K0, SY[k], ay0);
            az0 = fmaf(K0, SZ[k], az0);

            float r21 = fmaf(px1, AX[k], fmaf(py1, AY[k],
                        fmaf(pz1, AZ[k], AW[k] + pp1)));
            r21 = fmaxf(r21, 1e-12f);
            float K1 = r21 * __log2f(r21);
            ax1 = fmaf(K1, SX[k], ax1);
            ay1 = fmaf(K1, SY[k], ay1);
            az1 = fmaf(K1, SZ[k], az1);
        }
    }

    // Cross-wave reduction through LDS.
    red[wave][lane][0] = ax0; red[wave][lane][1] = ay0; red[wave][lane][2] = az0;
    red[wave][lane][3] = ax1; red[wave][lane][4] = ay1; red[wave][lane][5] = az1;
    __syncthreads();

    if (t < 128) {
        const int l = t & 63, s = t >> 6;   // point p = nbase + t
        float rx = 0.f, ry = 0.f, rz = 0.f;
        #pragma unroll
        for (int w = 0; w < 4; ++w) {
            rx += red[w][l][3 * s + 0];
            ry += red[w][l][3 * s + 1];
            rz += red[w][l][3 * s + 2];
        }
        float* op = out + ((size_t)b * N_PTS + nbase + t) * 3;
        op[0] = rx; op[1] = ry; op[2] = rz;
    }
}

extern "C" void kernel_launch(void* const* d_in, const int* in_sizes, int n_in,
                              void* d_out, int out_size, void* d_ws, size_t ws_size,
                              hipStream_t stream) {
    const float* sparse_disp    = (const float*)d_in[0];
    const float* original_cp    = (const float*)d_in[1];
    const float* original_dense = (const float*)d_in[2];
    float* out = (float*)d_out;

    dim3 grid(BATCH * (N_PTS / 128));   // 1024 blocks
    dim3 block(256);
    rbf_tps_kernel<<<grid, block, 0, stream>>>(sparse_disp, original_cp,
                                               original_dense, out);
}